// Round 15
// baseline (114.649 us; speedup 1.0000x reference)
//
#include <hip/hip_runtime.h>

// SparseMatmul3D: out[b,n,m] = sum_k x[b,n,k] * y[b,m,k]
// B=4, N=M=4096, D=64, fp32 in/out. Write-bound (268 MB out, floor ~38us @7TB/s).
// R1-R11: every tiling/order/NT/density/aspect variant pins at ~90us (~3 TB/s).
// R12: probe_tile (exact R8 pattern, pure stores) -> 6.2+ TB/s. Pattern innocent.
// R13: per-wave pipeline -> 97us. R14: producer/consumer role split -> 96.8us,
//   BUT __syncthreads drains vmcnt(0) every iteration (gfx950 emits
//   s_waitcnt vmcnt(0) before s_barrier) -> writer store queue forcibly
//   emptied 16x -> bursty stream again. Also only 1 block/CU (128KB LDS).
// R15: non-draining handoff: s_waitcnt(lgkmcnt(0) only, vmcnt untouched) +
//   raw s_barrier; 64x128 tiles (2x32KB LDS) -> 2 blocks/CU, 16 waves/CU.
//   Stores stay in flight across all iterations.

#define BATCH 4
#define NN 4096
#define MM 4096
#define DD 64
#define NBLK 512
#define TPB 16   // 8192 tiles / 512 blocks

typedef __attribute__((ext_vector_type(8))) short bf16x8;
typedef __attribute__((ext_vector_type(4))) float f32x4;

__device__ __forceinline__ unsigned short f2bf(float f) {
    unsigned u = __builtin_bit_cast(unsigned, f);
    u += 0x7FFFu + ((u >> 16) & 1u);   // round-to-nearest-even
    return (unsigned short)(u >> 16);
}

__device__ __forceinline__ bf16x8 load8_bf16(const float* __restrict__ p) {
    f32x4 v0 = *reinterpret_cast<const f32x4*>(p);
    f32x4 v1 = *reinterpret_cast<const f32x4*>(p + 4);
    bf16x8 r;
    r[0] = (short)f2bf(v0[0]); r[1] = (short)f2bf(v0[1]);
    r[2] = (short)f2bf(v0[2]); r[3] = (short)f2bf(v0[3]);
    r[4] = (short)f2bf(v1[0]); r[5] = (short)f2bf(v1[1]);
    r[6] = (short)f2bf(v1[2]); r[7] = (short)f2bf(v1[3]);
    return r;
}

__global__ __launch_bounds__(512, 4) void
SparseMatmul3D_36155034698289_kernel(const float* __restrict__ x,
                                     const float* __restrict__ y,
                                     float* __restrict__ out) {
    __shared__ float lds[2][64 * 128];   // 2 x 32 KB double buffer

    const int bid   = blockIdx.x;
    const int tid   = threadIdx.x;
    const int w     = tid >> 6;          // 0..7
    const int lane  = tid & 63;
    const int row16 = lane & 15;
    const int kgrp  = lane >> 4;
    const bool writer = (w >= 4);
    const int  sw     = w & 3;           // role-local wave index

#pragma unroll 1
    for (int g = 0; g <= TPB; ++g) {
        if (!writer && g < TPB) {
            // ---- compute tile T into lds[g&1] ----
            const int T   = g * NBLK + bid;          // [0,8192)
            const int b   = T >> 11;
            const int ntl = (T >> 5) & 63;
            const int mc  = T & 31;
            const int n0  = ntl * 64;
            const int m0  = mc * 128 + sw * 32;      // this wave's 32-wide m slice

            const float* __restrict__ xb = x + (size_t)b * NN * DD;
            const float* __restrict__ yb = y + (size_t)b * MM * DD;

            bf16x8 bfrag[4][2];
#pragma unroll
            for (int j = 0; j < 4; ++j) {
                const float* p = xb + (size_t)(n0 + j * 16 + row16) * DD + kgrp * 8;
                bfrag[j][0] = load8_bf16(p);
                bfrag[j][1] = load8_bf16(p + 32);
            }

            bf16x8 af[2][2];
#pragma unroll
            for (int i = 0; i < 2; ++i) {
                const float* p = yb + (size_t)(m0 + i * 16 + row16) * DD + kgrp * 8;
                af[i][0] = load8_bf16(p);
                af[i][1] = load8_bf16(p + 32);
            }

            f32x4 acc[2][4];
#pragma unroll
            for (int i = 0; i < 2; ++i)
#pragma unroll
                for (int j = 0; j < 4; ++j)
                    acc[i][j] = (f32x4){0.f, 0.f, 0.f, 0.f};

#pragma unroll
            for (int ks = 0; ks < 2; ++ks)
#pragma unroll
                for (int i = 0; i < 2; ++i)
#pragma unroll
                    for (int j = 0; j < 4; ++j)
                        acc[i][j] = __builtin_amdgcn_mfma_f32_16x16x32_bf16(
                            af[i][ks], bfrag[j][ks], acc[i][j], 0, 0, 0);

            // stage: D layout col=lane&15=n-local, row=kgrp*4+reg=m-local
            float* __restrict__ buf = lds[g & 1];
#pragma unroll
            for (int j = 0; j < 4; ++j) {
                const int nl = j * 16 + row16;
#pragma unroll
                for (int i = 0; i < 2; ++i) {
                    const int ml = sw * 32 + i * 16 + kgrp * 4;
                    *reinterpret_cast<f32x4*>(
                        &buf[nl * 128 + (ml ^ ((nl & 7) << 2))]) = acc[i][j];
                }
            }
        } else if (writer && g > 0) {
            // ---- drain tile g-1 from lds[(g-1)&1]: pure-store stream ----
            const int T   = (g - 1) * NBLK + bid;
            const int b   = T >> 11;
            const int ntl = (T >> 5) & 63;
            const int mc  = T & 31;
            const int n0  = ntl * 64;
            const int mb  = mc * 128;

            const float* __restrict__ buf = lds[(g - 1) & 1];
            float* __restrict__ ob = out + (size_t)b * NN * MM;
#pragma unroll
            for (int s = 0; s < 8; ++s) {
                const int row = sw * 16 + s * 2 + (lane >> 5);
                const int col = (lane & 31) * 4;
                f32x4 v = *reinterpret_cast<const f32x4*>(
                    &buf[row * 128 + (col ^ ((row & 7) << 2))]);
                *reinterpret_cast<f32x4*>(ob + (size_t)(n0 + row) * MM + mb + col) = v;
            }
        }

        if (g < TPB) {
            // Non-draining handoff: wait LDS ops only (lgkmcnt(0)); vmcnt=63,
            // expcnt=7 untouched -> stores stay in flight across the barrier.
            __builtin_amdgcn_sched_barrier(0);
            __builtin_amdgcn_s_waitcnt(0xC07F);
            __builtin_amdgcn_s_barrier();
            __builtin_amdgcn_sched_barrier(0);
        }
    }
}

extern "C" void kernel_launch(void* const* d_in, const int* in_sizes, int n_in,
                              void* d_out, int out_size, void* d_ws, size_t ws_size,
                              hipStream_t stream) {
    const float* x = (const float*)d_in[0];
    const float* y = (const float*)d_in[1];
    float* out = (float*)d_out;

    dim3 grid(NBLK);
    dim3 block(512);
    SparseMatmul3D_36155034698289_kernel<<<grid, block, 0, stream>>>(x, y, out);
}

// Round 16
// 57.502 us; speedup vs baseline: 1.9938x; 1.9938x over previous
//
#include <hip/hip_runtime.h>

// SparseMatmul3D: out[b,n,m] = sum_k x[b,n,k] * y[b,m,k]
// B=4, N=M=4096, D=64, fp32 in/out. Write-bound (268 MB out, floor ~38us @7TB/s).
// R1-R15 ledger: all tiling/order/NT/density/aspect/role-split variants pin at
//   ~90us (3 TB/s); pure-store probes (R12) hit 6.3 TB/s in the same pattern.
// LAW (fits all 16 pts): store_BW ~ 6.3 TB/s x store_bytes/(load+store bytes)
//   through the CU vmem port. R1's 1:1 ratio (50%) was the historical floor.
// R16: 256x256-tile LDS GEMM -> 128 KB loads vs 256 KB stores per block (67%).
//   Fragments come from swizzled bf16 LDS via ds_read (lgkm domain - no vmcnt
//   coupling with stores). One-shot blocks: stage -> sync -> MFMA+store -> end.

#define BATCH 4
#define NN 4096
#define MM 4096
#define DD 64

typedef __attribute__((ext_vector_type(8))) short bf16x8;
typedef __attribute__((ext_vector_type(4))) float f32x4;

__device__ __forceinline__ unsigned short f2bf(float f) {
    unsigned u = __builtin_bit_cast(unsigned, f);
    u += 0x7FFFu + ((u >> 16) & 1u);   // round-to-nearest-even
    return (unsigned short)(u >> 16);
}

__device__ __forceinline__ bf16x8 cvt8(f32x4 v0, f32x4 v1) {
    bf16x8 r;
    r[0] = (short)f2bf(v0[0]); r[1] = (short)f2bf(v0[1]);
    r[2] = (short)f2bf(v0[2]); r[3] = (short)f2bf(v0[3]);
    r[4] = (short)f2bf(v1[0]); r[5] = (short)f2bf(v1[1]);
    r[6] = (short)f2bf(v1[2]); r[7] = (short)f2bf(v1[3]);
    return r;
}

// Stage one 256x64-f32 contiguous panel into XOR-swizzled bf16 LDS.
// Thread t, iter u: covers f32 [u*4096 + t*8, +8) -> row r=f/64, units t&7,
// swizzled unit = (t&7) ^ (r&7). Bijective; ds_write spread across all units.
__device__ __forceinline__ void stage_panel(const float* __restrict__ src,
                                            short* __restrict__ dst, int t) {
#pragma unroll
    for (int u = 0; u < 4; ++u) {
        const int f = u * 4096 + t * 8;
        f32x4 v0 = *reinterpret_cast<const f32x4*>(src + f);
        f32x4 v1 = *reinterpret_cast<const f32x4*>(src + f + 4);
        const int r  = (u << 6) + (t >> 3);
        const int un = (t & 7) ^ (r & 7);
        *reinterpret_cast<bf16x8*>(&dst[r * 64 + un * 8]) = cvt8(v0, v1);
    }
}

__global__ __launch_bounds__(512, 4) void
SparseMatmul3D_36155034698289_kernel(const float* __restrict__ x,
                                     const float* __restrict__ y,
                                     float* __restrict__ out) {
    const int bid = blockIdx.x;          // [0,1024)
    const int mc  = bid & 15;            // m-tile (fastest)
    const int nt  = (bid >> 4) & 15;     // n-tile
    const int b   = bid >> 8;            // batch
    const int n0  = nt * 256;
    const int m0  = mc * 256;

    const int tid   = threadIdx.x;
    const int w     = tid >> 6;          // 8 waves
    const int lane  = tid & 63;
    const int row16 = lane & 15;
    const int kgrp  = lane >> 4;
    const int wr    = w >> 1;            // n quarter [0,4)
    const int wcp   = (w & 1) * 2;       // m subtile pair base
    const int nloc  = wr * 64;

    __shared__ short xs[256 * 64];       // 32 KB bf16 x-panel (n rows)
    __shared__ short ys[256 * 64];       // 32 KB bf16 y-panel (m rows)

    stage_panel(x + (size_t)b * NN * DD + (size_t)n0 * DD, xs, tid);
    stage_panel(y + (size_t)b * MM * DD + (size_t)m0 * DD, ys, tid);
    __syncthreads();   // drains staging loads only; no stores in flight yet

    float* __restrict__ ob = out + (size_t)b * NN * MM;

#pragma unroll
    for (int tt = 0; tt < 2; ++tt) {
        const int mloc = (wcp + tt) * 64;

        f32x4 acc[4][4];
#pragma unroll
        for (int i = 0; i < 4; ++i)
#pragma unroll
            for (int j = 0; j < 4; ++j)
                acc[i][j] = (f32x4){0.f, 0.f, 0.f, 0.f};

#pragma unroll
        for (int i = 0; i < 4; ++i) {
            const int ra = mloc + i * 16 + row16;
            const bf16x8 a0 = *reinterpret_cast<const bf16x8*>(
                &ys[ra * 64 + ((kgrp       ^ (ra & 7)) * 8)]);
            const bf16x8 a1 = *reinterpret_cast<const bf16x8*>(
                &ys[ra * 64 + (((4 | kgrp) ^ (ra & 7)) * 8)]);
#pragma unroll
            for (int j = 0; j < 4; ++j) {
                const int rb = nloc + j * 16 + row16;
                const bf16x8 b0 = *reinterpret_cast<const bf16x8*>(
                    &xs[rb * 64 + ((kgrp       ^ (rb & 7)) * 8)]);
                const bf16x8 b1 = *reinterpret_cast<const bf16x8*>(
                    &xs[rb * 64 + (((4 | kgrp) ^ (rb & 7)) * 8)]);
                acc[i][j] = __builtin_amdgcn_mfma_f32_16x16x32_bf16(
                    a0, b0, acc[i][j], 0, 0, 0);
                acc[i][j] = __builtin_amdgcn_mfma_f32_16x16x32_bf16(
                    a1, b1, acc[i][j], 0, 0, 0);
            }
        }

        // Stores: D layout col=lane&15=n, row=kgrp*4+reg=m (4 consecutive m).
        // ds_reads of next tile are lgkm-domain: stores stay in flight.
#pragma unroll
        for (int j = 0; j < 4; ++j) {
            float* orow = ob + (size_t)(n0 + nloc + j * 16 + row16) * MM;
#pragma unroll
            for (int i = 0; i < 4; ++i)
                *reinterpret_cast<f32x4*>(
                    orow + m0 + mloc + i * 16 + kgrp * 4) = acc[i][j];
        }
    }
}

extern "C" void kernel_launch(void* const* d_in, const int* in_sizes, int n_in,
                              void* d_out, int out_size, void* d_ws, size_t ws_size,
                              hipStream_t stream) {
    const float* x = (const float*)d_in[0];
    const float* y = (const float*)d_in[1];
    float* out = (float*)d_out;

    dim3 grid(1024);
    dim3 block(512);
    SparseMatmul3D_36155034698289_kernel<<<grid, block, 0, stream>>>(x, y, out);
}